// Round 3
// baseline (102.309 us; speedup 1.0000x reference)
//
#include <hip/hip_runtime.h>
#include <hip/hip_bf16.h>

#define BB 4
#define NN 4096
#define DD 64
#define CCF 16               // fea column chunks
#define FEA_BLOCKS 1024      // 16 rowchunks * 4 batches * 16 colchunks
#define PT_BLOCKS 512        // 8 rowgroups(2048 rows) * 64 jchunks(64 cols)
#define HPB 1024             // hit capacity per point block (expect ~84)
#define PSCALE 240.2244818f  // 200 * sqrt(log2(e)) : |p'i-p'j|^2 = PD*log2e
#define K2L 2.885390082f     // 2*log2(e)  (folded into f1 bf16)
#define NL2E -1.442695041f   // -log2(e)
#define LN2 0.6931471805599453f

typedef __attribute__((ext_vector_type(8))) short bf16x8;
typedef __attribute__((ext_vector_type(4))) float f32x4;

// workspace layout (bytes); harness ws is 256MiB (poison fill showed 268MB)
static constexpr size_t BN = (size_t)BB * NN;
static constexpr size_t OFF_F1B = 0;                          // bf16 [BN][D] (pre-scaled by K2L)
static constexpr size_t OFF_F2B = OFF_F1B + BN * DD * 2;      // bf16 [BN][D]
static constexpr size_t OFF_PP4 = OFF_F2B + BN * DD * 2;      // float4 [BN] {p'x,p'y,p'z,|p'|^2}
static constexpr size_t OFF_NB2 = OFF_PP4 + BN * 16;          // f32 [BN]  -|f2|^2*log2e
static constexpr size_t OFF_PZF = OFF_NB2 + BN * 4;           // f32 [CCF][BN] partial Zf
static constexpr size_t OFF_CNT = OFF_PZF + (size_t)CCF * BN * 4;   // u32 [PT_BLOCKS]
static constexpr size_t OFF_ZP  = OFF_CNT + PT_BLOCKS * 4;    // f32 [BN]
static constexpr size_t OFF_SP  = OFF_ZP + BN * 4;            // f32 [BN]
static constexpr size_t OFF_HIT = OFF_SP + BN * 4;            // uint2 [PT_BLOCKS][HPB]
static constexpr size_t CLR_BYTES = OFF_HIT - OFF_CNT;        // cnt+Zp+Sp zeroed per call

__device__ __forceinline__ unsigned short f2bf(float x) {
  unsigned int u = __float_as_uint(x);
  u += 0x7FFFu + ((u >> 16) & 1u);   // round-to-nearest-even
  return (unsigned short)(u >> 16);
}
__device__ __forceinline__ float bf2f(short s) {
  return __uint_as_float(((unsigned)(unsigned short)s) << 16);
}
__device__ __forceinline__ void gl_lds16(const void* g, void* lds) {
  __builtin_amdgcn_global_load_lds((const __attribute__((address_space(1))) unsigned int*)g,
                                   (__attribute__((address_space(3))) unsigned int*)lds, 16, 0, 0);
}
__device__ __forceinline__ void gl_lds4(const void* g, void* lds) {
  __builtin_amdgcn_global_load_lds((const __attribute__((address_space(1))) unsigned int*)g,
                                   (__attribute__((address_space(3))) unsigned int*)lds, 4, 0, 0);
}

// ---------------- prep: bf16 convert (f1 scaled by K2L) + norms + points + reg ----
__global__ __launch_bounds__(256) void prep_kernel(
    const float* __restrict__ pts, const float* __restrict__ f1,
    const float* __restrict__ f2, unsigned short* __restrict__ f1b,
    unsigned short* __restrict__ f2b, float4* __restrict__ pp4,
    float* __restrict__ nb2, float* __restrict__ out) {
  const int R0 = blockIdx.x * 32;
  const int t = threadIdx.x;
  const float4* f1v = (const float4*)(f1 + (size_t)R0 * DD);
  const float4* f2v = (const float4*)(f2 + (size_t)R0 * DD);
  ushort4* o1 = (ushort4*)(f1b + (size_t)R0 * DD);
  ushort4* o2 = (ushort4*)(f2b + (size_t)R0 * DD);
  float regsum = 0.f;
#pragma unroll
  for (int p = 0; p < 2; ++p) {
    int c = t + p * 256;                 // float4-chunk in [0,512); row = R0 + c/16
    float4 a = f1v[c], bv = f2v[c];
    ushort4 ua, ub;
    ua.x = f2bf(a.x * K2L); ua.y = f2bf(a.y * K2L);
    ua.z = f2bf(a.z * K2L); ua.w = f2bf(a.w * K2L);
    ub.x = f2bf(bv.x); ub.y = f2bf(bv.y); ub.z = f2bf(bv.z); ub.w = f2bf(bv.w);
    o1[c] = ua; o2[c] = ub;
    float s1 = a.x * a.x + a.y * a.y + a.z * a.z + a.w * a.w;
    float s2 = bv.x * bv.x + bv.y * bv.y + bv.z * bv.z + bv.w * bv.w;
    regsum += s1 + s2;
    float s2r = s2;
#pragma unroll
    for (int m = 1; m <= 8; m <<= 1) s2r += __shfl_xor(s2r, m, 64);
    if ((t & 15) == 0) nb2[R0 + (c >> 4)] = NL2E * s2r;
  }
  if (t < 32) {
    int row = R0 + t;
    float px = pts[row * 3 + 0] * PSCALE;
    float py = pts[row * 3 + 1] * PSCALE;
    float pz = pts[row * 3 + 2] * PSCALE;
    pp4[row] = make_float4(px, py, pz, fmaf(px, px, fmaf(py, py, pz * pz)));
  }
  __shared__ float red[256];
  red[t] = regsum;
  __syncthreads();
  for (int k = 128; k > 0; k >>= 1) {
    if (t < k) red[t] += red[t + k];
    __syncthreads();
  }
  if (t == 0) atomicAdd(&out[BB + R0 / NN], red[0] * (1.f / ((float)NN * DD)));
}

// ---------------- main: fea blocks (Zf) + point blocks (hit emission) ----------
__global__ __launch_bounds__(256) void main_kernel(
    const unsigned short* __restrict__ f1b, const unsigned short* __restrict__ f2b,
    const float4* __restrict__ pp4, const float* __restrict__ nb2g,
    float* __restrict__ pZf, unsigned int* __restrict__ cnt, uint2* __restrict__ hits) {
  __shared__ __align__(16) unsigned char smem[16384 + 512];
  const int bid = blockIdx.x;
  const int tid = threadIdx.x;
  const int wave = tid >> 6, lane = tid & 63;

  if (bid < FEA_BLOCKS) {
    // ---- fea: Zf_i += 2^(K2L*dot(f1_i,f2_j) + nb2_j); wave owns 64 rows ----
    const int ck = bid & 15, b = (bid >> 4) & 3, rc = bid >> 6;
    const int l15 = lane & 15, l4 = lane >> 4;
    const int rowloc0 = rc * 256 + wave * 64;
    bf16x8 af[4][2];
#pragma unroll
    for (int rt = 0; rt < 4; ++rt) {
      const unsigned short* fr = f1b + ((size_t)(b * NN + rowloc0 + rt * 16 + l15)) * DD;
      af[rt][0] = *(const bf16x8*)(fr + l4 * 8);
      af[rt][1] = *(const bf16x8*)(fr + 32 + l4 * 8);
    }
    float Zf[4][4];
#pragma unroll
    for (int rt = 0; rt < 4; ++rt)
#pragma unroll
      for (int r = 0; r < 4; ++r) Zf[rt][r] = 0.f;

    const int colbase = ck * 256;
    auto stage = [&](int buf, int col0) {
      const char* gbase = (const char*)(f2b + ((size_t)(b * NN + col0)) * DD);
      int r0 = tid >> 3, s0 = tid & 7;
      gl_lds16(gbase + r0 * 128 + (s0 ^ (r0 & 7)) * 16, smem + buf * 8192 + wave * 1024);
      int c1 = tid + 256, r1 = c1 >> 3, s1 = c1 & 7;
      gl_lds16(gbase + r1 * 128 + (s1 ^ (r1 & 7)) * 16, smem + buf * 8192 + wave * 1024 + 4096);
      if (wave == 1) gl_lds4(nb2g + (b * NN + col0 + lane), smem + 16384 + buf * 256);
    };
    stage(0, colbase);
    const int swz0 = ((l4 ^ (l15 & 7)) << 4);
    const int swz1 = (((4 + l4) ^ (l15 & 7)) << 4);
    const float* b2t = (const float*)(smem + 16384);

    for (int jt = 0; jt < 4; ++jt) {
      __syncthreads();
      if (jt < 3) stage((jt + 1) & 1, colbase + (jt + 1) * 64);
      const int cur = jt & 1;
      const char* f2c = (const char*)smem + cur * 8192 + l15 * 128;
#pragma unroll
      for (int s16 = 0; s16 < 4; ++s16) {
        bf16x8 bf0 = *(const bf16x8*)(f2c + s16 * 2048 + swz0);
        bf16x8 bf1 = *(const bf16x8*)(f2c + s16 * 2048 + swz1);
        float nb = b2t[cur * 64 + s16 * 16 + l15];
        f32x4 a0 = {nb, nb, nb, nb}, a1 = a0, a2 = a0, a3 = a0;
        a0 = __builtin_amdgcn_mfma_f32_16x16x32_bf16(af[0][0], bf0, a0, 0, 0, 0);
        a1 = __builtin_amdgcn_mfma_f32_16x16x32_bf16(af[1][0], bf0, a1, 0, 0, 0);
        a2 = __builtin_amdgcn_mfma_f32_16x16x32_bf16(af[2][0], bf0, a2, 0, 0, 0);
        a3 = __builtin_amdgcn_mfma_f32_16x16x32_bf16(af[3][0], bf0, a3, 0, 0, 0);
        a0 = __builtin_amdgcn_mfma_f32_16x16x32_bf16(af[0][1], bf1, a0, 0, 0, 0);
        a1 = __builtin_amdgcn_mfma_f32_16x16x32_bf16(af[1][1], bf1, a1, 0, 0, 0);
        a2 = __builtin_amdgcn_mfma_f32_16x16x32_bf16(af[2][1], bf1, a2, 0, 0, 0);
        a3 = __builtin_amdgcn_mfma_f32_16x16x32_bf16(af[3][1], bf1, a3, 0, 0, 0);
#pragma unroll
        for (int r = 0; r < 4; ++r) {
          Zf[0][r] += __builtin_amdgcn_exp2f(a0[r]);
          Zf[1][r] += __builtin_amdgcn_exp2f(a1[r]);
          Zf[2][r] += __builtin_amdgcn_exp2f(a2[r]);
          Zf[3][r] += __builtin_amdgcn_exp2f(a3[r]);
        }
      }
    }
#pragma unroll
    for (int m = 1; m <= 8; m <<= 1)
#pragma unroll
      for (int rt = 0; rt < 4; ++rt)
#pragma unroll
        for (int r = 0; r < 4; ++r) Zf[rt][r] += __shfl_xor(Zf[rt][r], m, 64);
    if (l15 == 0) {
      size_t base = (size_t)ck * BN + b * NN + rowloc0;
#pragma unroll
      for (int rt = 0; rt < 4; ++rt)
#pragma unroll
        for (int r = 0; r < 4; ++r) pZf[base + rt * 16 + l4 * 4 + r] = Zf[rt][r];
    }
  } else {
    // ---- point: PD2 for 2048 rows x 64 cols; emit hits (PD2 < 126) ----
    const int pb = bid - FEA_BLOCKS;
    const int rg = pb >> 6, jc = pb & 63;
    const int row0 = rg * 2048;            // global row base (within one batch)
    const int b = row0 >> 12;
    const int jcol0 = b * NN + jc * 64;    // global index of j-chunk in pp4
    if (wave == 0) gl_lds16(pp4 + jcol0 + lane, smem);
    float m2x[8], m2y[8], m2z[8], xw[8];
#pragma unroll
    for (int k = 0; k < 8; ++k) {
      float4 p = pp4[row0 + k * 256 + tid];
      m2x[k] = -2.f * p.x; m2y[k] = -2.f * p.y; m2z[k] = -2.f * p.z; xw[k] = p.w;
    }
    __syncthreads();
    const float4* ptj = (const float4*)smem;
#pragma unroll 4
    for (int jj = 0; jj < 64; ++jj) {
      float4 pj = ptj[jj];
      float pd[8];
#pragma unroll
      for (int k = 0; k < 8; ++k)
        pd[k] = fmaf(m2x[k], pj.x, fmaf(m2y[k], pj.y, fmaf(m2z[k], pj.z, xw[k] + pj.w)));
      float mn = fminf(fminf(fminf(pd[0], pd[1]), fminf(pd[2], pd[3])),
                       fminf(fminf(pd[4], pd[5]), fminf(pd[6], pd[7])));
      if (mn < 126.f) {
#pragma unroll
        for (int k = 0; k < 8; ++k)
          if (pd[k] < 126.f) {
            unsigned slot = atomicAdd(&cnt[pb], 1u);
            if (slot < HPB) {
              unsigned rowg = row0 + k * 256 + tid;
              hits[(size_t)pb * HPB + slot] =
                  make_uint2((rowg << 12) | (unsigned)(jc * 64 + jj), __float_as_uint(pd[k]));
            }
          }
      }
    }
  }
}

// ---------------- pass3: sparse hits -> Zp, Sp (per-row) ----------------------
__global__ __launch_bounds__(256) void pass3_kernel(
    const unsigned short* __restrict__ f1b, const unsigned short* __restrict__ f2b,
    const float* __restrict__ nb2g, const unsigned int* __restrict__ cnt,
    const uint2* __restrict__ hits, float* __restrict__ Zp, float* __restrict__ Sp) {
  const int p = blockIdx.x;
  unsigned n = cnt[p]; if (n > HPB) n = HPB;
  for (unsigned idx = threadIdx.x; idx < n; idx += 256) {
    uint2 h = hits[(size_t)p * HPB + idx];
    unsigned rowg = h.x >> 12, jloc = h.x & 4095u;
    unsigned jg = ((rowg >> 12) << 12) + jloc;
    const bf16x8* A = (const bf16x8*)(f1b + (size_t)rowg * DD);
    const bf16x8* Bv = (const bf16x8*)(f2b + (size_t)jg * DD);
    float dot = 0.f;
#pragma unroll
    for (int c = 0; c < 8; ++c) {
      bf16x8 av = A[c], bv = Bv[c];
#pragma unroll
      for (int e = 0; e < 8; ++e) dot = fmaf(bf2f(av[e]), bf2f(bv[e]), dot);
    }
    float t2 = dot + nb2g[jg];                       // (2dot - b2)*log2e
    float g = __builtin_amdgcn_exp2f(-__uint_as_float(h.y));
    atomicAdd(&Zp[rowg], g);
    atomicAdd(&Sp[rowg], g * t2);
  }
}

// ---------------- finalize: ce per row, reduce per batch ----------------------
__global__ __launch_bounds__(256) void finalize_kernel(
    const float* __restrict__ pZf, const float* __restrict__ Zp,
    const float* __restrict__ Sp, const float* __restrict__ wts,
    float* __restrict__ out) {
  const int i = blockIdx.x * 256 + threadIdx.x;    // row in [0, BN)
  float zf = 0.f;
#pragma unroll
  for (int c = 0; c < CCF; ++c) zf += pZf[(size_t)c * BN + i];
  float ce = wts[i] * (LN2 * (__builtin_amdgcn_logf(zf) - Sp[i] / Zp[i]));
  __shared__ float red[256];
  red[threadIdx.x] = ce;
  __syncthreads();
  for (int k = 128; k > 0; k >>= 1) {
    if (threadIdx.x < k) red[threadIdx.x] += red[threadIdx.x + k];
    __syncthreads();
  }
  if (threadIdx.x == 0) atomicAdd(&out[i >> 12], red[0]);
}

extern "C" void kernel_launch(void* const* d_in, const int* in_sizes, int n_in,
                              void* d_out, int out_size, void* d_ws, size_t ws_size,
                              hipStream_t stream) {
  const float* pts = (const float*)d_in[0];
  const float* f1  = (const float*)d_in[1];
  const float* f2  = (const float*)d_in[2];
  const float* wts = (const float*)d_in[3];
  float* out = (float*)d_out;
  char* ws = (char*)d_ws;

  unsigned short* f1b = (unsigned short*)(ws + OFF_F1B);
  unsigned short* f2b = (unsigned short*)(ws + OFF_F2B);
  float4* pp4 = (float4*)(ws + OFF_PP4);
  float* nb2 = (float*)(ws + OFF_NB2);
  float* pZf = (float*)(ws + OFF_PZF);
  unsigned int* cnt = (unsigned int*)(ws + OFF_CNT);
  float* Zp = (float*)(ws + OFF_ZP);
  float* Sp = (float*)(ws + OFF_SP);
  uint2* hits = (uint2*)(ws + OFF_HIT);

  hipMemsetAsync(d_out, 0, 8 * sizeof(float), stream);
  hipMemsetAsync(ws + OFF_CNT, 0, CLR_BYTES, stream);

  prep_kernel<<<BN / 32, 256, 0, stream>>>(pts, f1, f2, f1b, f2b, pp4, nb2, out);
  main_kernel<<<FEA_BLOCKS + PT_BLOCKS, 256, 0, stream>>>(f1b, f2b, pp4, nb2, pZf, cnt, hits);
  pass3_kernel<<<PT_BLOCKS, 256, 0, stream>>>(f1b, f2b, nb2, cnt, hits, Zp, Sp);
  finalize_kernel<<<BN / 256, 256, 0, stream>>>(pZf, Zp, Sp, wts, out);
}

// Round 4
// 78.718 us; speedup vs baseline: 1.2997x; 1.2997x over previous
//
#include <hip/hip_runtime.h>
#include <hip/hip_bf16.h>

#define BB 4
#define NN 4096
#define DD 64
#define TJ 64
#define CC 8                 // fea column chunks (grid.z)
#define CHUNK (NN / CC)      // 512 cols per fea block
#define NTC (CHUNK / TJ)     // 8 tiles per fea block
#define PT_BLOCKS 512        // 8 rowgroups(2048 rows) * 64 jchunks(64 cols)
#define HPB 1024             // hit capacity per point block (expect ~88)
#define PSCALE 240.2244818f  // 200 * sqrt(log2(e)) : |p'i-p'j|^2 = PD*log2(e)
#define K2L 2.885390082f     // 2*log2(e)  (folded into f1 bf16)
#define NL2E -1.442695041f   // -log2(e)
#define LN2 0.6931471805599453f

typedef __attribute__((ext_vector_type(8))) short bf16x8;
typedef __attribute__((ext_vector_type(4))) float f32x4;

// workspace layout (bytes)
static constexpr size_t BN = (size_t)BB * NN;
static constexpr size_t OFF_F1B = 0;                          // bf16 [BN][D] (pre-scaled by K2L)
static constexpr size_t OFF_F2B = OFF_F1B + BN * DD * 2;      // bf16 [BN][D]
static constexpr size_t OFF_PP4 = OFF_F2B + BN * DD * 2;      // float4 [BN] {p'x,p'y,p'z,|p'|^2}
static constexpr size_t OFF_NB2 = OFF_PP4 + BN * 16;          // f32 [BN]  -|f2|^2*log2e
static constexpr size_t OFF_PZF = OFF_NB2 + BN * 4;           // f32 [CC][BN] partial Zf
static constexpr size_t OFF_ZP  = OFF_PZF + (size_t)CC * BN * 4;  // f32 [BN]
static constexpr size_t OFF_SP  = OFF_ZP + BN * 4;            // f32 [BN]
static constexpr size_t CLR_BYTES = OFF_SP + BN * 4 - OFF_ZP; // Zp+Sp zeroed per call

__device__ __forceinline__ unsigned short f2bf(float x) {
  unsigned int u = __float_as_uint(x);
  u += 0x7FFFu + ((u >> 16) & 1u);   // round-to-nearest-even
  return (unsigned short)(u >> 16);
}
__device__ __forceinline__ float bf2f(short s) {
  return __uint_as_float(((unsigned)(unsigned short)s) << 16);
}
__device__ __forceinline__ void gl_lds16(const void* g, void* lds) {
  __builtin_amdgcn_global_load_lds((const __attribute__((address_space(1))) unsigned int*)g,
                                   (__attribute__((address_space(3))) unsigned int*)lds, 16, 0, 0);
}
__device__ __forceinline__ void gl_lds4(const void* g, void* lds) {
  __builtin_amdgcn_global_load_lds((const __attribute__((address_space(1))) unsigned int*)g,
                                   (__attribute__((address_space(3))) unsigned int*)lds, 4, 0, 0);
}

// ---------------- prep: bf16 convert (f1 scaled by K2L) + norms + points + reg ----
__global__ __launch_bounds__(256) void prep_kernel(
    const float* __restrict__ pts, const float* __restrict__ f1,
    const float* __restrict__ f2, unsigned short* __restrict__ f1b,
    unsigned short* __restrict__ f2b, float4* __restrict__ pp4,
    float* __restrict__ nb2, float* __restrict__ out) {
  const int R0 = blockIdx.x * 32;
  const int t = threadIdx.x;
  const float4* f1v = (const float4*)(f1 + (size_t)R0 * DD);
  const float4* f2v = (const float4*)(f2 + (size_t)R0 * DD);
  ushort4* o1 = (ushort4*)(f1b + (size_t)R0 * DD);
  ushort4* o2 = (ushort4*)(f2b + (size_t)R0 * DD);
  float regsum = 0.f;
#pragma unroll
  for (int p = 0; p < 2; ++p) {
    int c = t + p * 256;                 // float4-chunk in [0,512); row = R0 + c/16
    float4 a = f1v[c], bv = f2v[c];
    ushort4 ua, ub;
    ua.x = f2bf(a.x * K2L); ua.y = f2bf(a.y * K2L);
    ua.z = f2bf(a.z * K2L); ua.w = f2bf(a.w * K2L);
    ub.x = f2bf(bv.x); ub.y = f2bf(bv.y); ub.z = f2bf(bv.z); ub.w = f2bf(bv.w);
    o1[c] = ua; o2[c] = ub;
    float s1 = a.x * a.x + a.y * a.y + a.z * a.z + a.w * a.w;
    float s2 = bv.x * bv.x + bv.y * bv.y + bv.z * bv.z + bv.w * bv.w;
    regsum += s1 + s2;
    float s2r = s2;
#pragma unroll
    for (int m = 1; m <= 8; m <<= 1) s2r += __shfl_xor(s2r, m, 64);
    if ((t & 15) == 0) nb2[R0 + (c >> 4)] = NL2E * s2r;
  }
  if (t < 32) {
    int row = R0 + t;
    float px = pts[row * 3 + 0] * PSCALE;
    float py = pts[row * 3 + 1] * PSCALE;
    float pz = pts[row * 3 + 2] * PSCALE;
    pp4[row] = make_float4(px, py, pz, fmaf(px, px, fmaf(py, py, pz * pz)));
  }
  __shared__ float red[256];
  red[t] = regsum;
  __syncthreads();
  for (int k = 128; k > 0; k >>= 1) {
    if (t < k) red[t] += red[t + k];
    __syncthreads();
  }
  if (t == 0) atomicAdd(&out[BB + R0 / NN], red[0] * (1.f / ((float)NN * DD)));
}

// ---------------- fea: Zf_i = sum_j 2^(K2L*dot + nb2_j)  (R2 skeleton) --------
// grid (NN/64, BB, CC), block 256. Wave owns 16 rows x 512 cols (8 tiles).
__global__ __launch_bounds__(256) void fea_kernel(
    const unsigned short* __restrict__ f1b, const unsigned short* __restrict__ f2b,
    const float* __restrict__ nb2g, float* __restrict__ pZf) {
  __shared__ unsigned short f2t[2][TJ * DD];   // 16KB, XOR-swizzled 16B chunks in 128B rows
  __shared__ float b2t[2][TJ];                 // 512B

  const int b = blockIdx.y;
  const int ck = blockIdx.z;
  const int rowbase = blockIdx.x * 64;
  const int tid = threadIdx.x;
  const int wave = tid >> 6;
  const int lane = tid & 63;
  const int l15 = lane & 15;
  const int l4 = lane >> 4;

  const unsigned short* f1row = f1b + ((size_t)(b * NN + rowbase + wave * 16 + l15)) * DD;
  bf16x8 af0 = *(const bf16x8*)(f1row + l4 * 8);
  bf16x8 af1 = *(const bf16x8*)(f1row + 32 + l4 * 8);

  float Zf[4] = {0.f, 0.f, 0.f, 0.f};

  auto stage = [&](int buf, int col0) {
    const char* gbase = (const char*)(f2b + ((size_t)(b * NN + col0)) * DD);
    {
      int r = tid >> 3, s = tid & 7;
      gl_lds16(gbase + r * 128 + (s ^ (r & 7)) * 16, (char*)&f2t[buf][0] + wave * 1024);
    }
    {
      int c = tid + 256, r = c >> 3, s = c & 7;
      gl_lds16(gbase + r * 128 + (s ^ (r & 7)) * 16, (char*)&f2t[buf][0] + wave * 1024 + 4096);
    }
    if (wave == 1) gl_lds4(nb2g + (b * NN + col0 + lane), (char*)&b2t[buf][0]);
  };

  const int colbase = ck * CHUNK;
  stage(0, colbase);

  const int swz0 = ((l4 ^ (l15 & 7)) << 4);
  const int swz1 = (((4 + l4) ^ (l15 & 7)) << 4);

  for (int jt = 0; jt < NTC; ++jt) {
    __syncthreads();
    if (jt + 1 < NTC) stage((jt + 1) & 1, colbase + (jt + 1) * TJ);
    const int cur = jt & 1;
    const char* f2c = (const char*)f2t + cur * 8192 + l15 * 128;
#pragma unroll
    for (int s16 = 0; s16 < 4; ++s16) {
      bf16x8 bf0 = *(const bf16x8*)(f2c + swz0 + s16 * 2048);
      bf16x8 bf1 = *(const bf16x8*)(f2c + swz1 + s16 * 2048);
      float nb = b2t[cur][s16 * 16 + l15];
      f32x4 acc = {nb, nb, nb, nb};
      acc = __builtin_amdgcn_mfma_f32_16x16x32_bf16(af0, bf0, acc, 0, 0, 0);
      acc = __builtin_amdgcn_mfma_f32_16x16x32_bf16(af1, bf1, acc, 0, 0, 0);
#pragma unroll
      for (int r = 0; r < 4; ++r) Zf[r] += __builtin_amdgcn_exp2f(acc[r]);
    }
  }

#pragma unroll
  for (int m = 1; m <= 8; m <<= 1)
#pragma unroll
    for (int r = 0; r < 4; ++r) Zf[r] += __shfl_xor(Zf[r], m, 64);

  if (l15 == 0) {
    size_t base = (size_t)ck * BN + b * NN + rowbase + wave * 16 + l4 * 4;
#pragma unroll
    for (int r = 0; r < 4; ++r) pZf[base + r] = Zf[r];
  }
}

// ---------------- point: PD2 sparse hits -> Zp, Sp (fused resolve) ------------
__global__ __launch_bounds__(256) void point_kernel(
    const float4* __restrict__ pp4, const unsigned short* __restrict__ f1b,
    const unsigned short* __restrict__ f2b, const float* __restrict__ nb2g,
    float* __restrict__ Zp, float* __restrict__ Sp) {
  __shared__ __align__(16) float4 ptj[64];   // 1KB j-chunk points
  __shared__ uint2 hbuf[HPB];                // 8KB hit buffer
  __shared__ unsigned hcnt;
  const int pb = blockIdx.x;
  const int tid = threadIdx.x;
  const int rg = pb >> 6, jc = pb & 63;
  const int row0 = rg * 2048;                // global row base
  const int b = row0 >> 12;
  const int jcol0 = b * NN + jc * 64;

  if (tid == 0) hcnt = 0;
  if (tid < 64) gl_lds16(pp4 + jcol0 + tid, ptj);
  float m2x[8], m2y[8], m2z[8], xw[8];
#pragma unroll
  for (int k = 0; k < 8; ++k) {
    float4 p = pp4[row0 + k * 256 + tid];
    m2x[k] = -2.f * p.x; m2y[k] = -2.f * p.y; m2z[k] = -2.f * p.z; xw[k] = p.w;
  }
  __syncthreads();

#pragma unroll 4
  for (int jj = 0; jj < 64; ++jj) {
    float4 pj = ptj[jj];
    float pd[8];
#pragma unroll
    for (int k = 0; k < 8; ++k)
      pd[k] = fmaf(m2x[k], pj.x, fmaf(m2y[k], pj.y, fmaf(m2z[k], pj.z, xw[k] + pj.w)));
    float mn = fminf(fminf(fminf(pd[0], pd[1]), fminf(pd[2], pd[3])),
                     fminf(fminf(pd[4], pd[5]), fminf(pd[6], pd[7])));
    if (mn < 126.f) {
#pragma unroll
      for (int k = 0; k < 8; ++k)
        if (pd[k] < 126.f) {
          unsigned slot = atomicAdd(&hcnt, 1u);
          if (slot < HPB)
            hbuf[slot] = make_uint2(((unsigned)(k * 256 + tid) << 6) | (unsigned)jj,
                                    __float_as_uint(pd[k]));
        }
    }
  }
  __syncthreads();

  unsigned n = hcnt; if (n > HPB) n = HPB;
  for (unsigned idx = tid; idx < n; idx += 256) {
    uint2 h = hbuf[idx];
    unsigned rowg = row0 + (h.x >> 6);
    unsigned jg = jcol0 + (h.x & 63u);
    const bf16x8* A = (const bf16x8*)(f1b + (size_t)rowg * DD);
    const bf16x8* Bv = (const bf16x8*)(f2b + (size_t)jg * DD);
    float dot = 0.f;                         // = K2L * dot(f1,f2) (f1 pre-scaled)
#pragma unroll
    for (int c = 0; c < 8; ++c) {
      bf16x8 av = A[c], bv = Bv[c];
#pragma unroll
      for (int e = 0; e < 8; ++e) dot = fmaf(bf2f(av[e]), bf2f(bv[e]), dot);
    }
    float t2 = dot + nb2g[jg];               // (2dot - b2)*log2e
    float g = __builtin_amdgcn_exp2f(-__uint_as_float(h.y));
    atomicAdd(&Zp[rowg], g);
    atomicAdd(&Sp[rowg], g * t2);
  }
}

// ---------------- finalize: ce per row, reduce per batch ----------------------
__global__ __launch_bounds__(256) void finalize_kernel(
    const float* __restrict__ pZf, const float* __restrict__ Zp,
    const float* __restrict__ Sp, const float* __restrict__ wts,
    float* __restrict__ out) {
  const int i = blockIdx.x * 256 + threadIdx.x;    // row in [0, BN)
  float zf = 0.f;
#pragma unroll
  for (int c = 0; c < CC; ++c) zf += pZf[(size_t)c * BN + i];
  float ce = wts[i] * (LN2 * (__builtin_amdgcn_logf(zf) - Sp[i] / Zp[i]));
  __shared__ float red[256];
  red[threadIdx.x] = ce;
  __syncthreads();
  for (int k = 128; k > 0; k >>= 1) {
    if (threadIdx.x < k) red[threadIdx.x] += red[threadIdx.x + k];
    __syncthreads();
  }
  if (threadIdx.x == 0) atomicAdd(&out[i >> 12], red[0]);
}

extern "C" void kernel_launch(void* const* d_in, const int* in_sizes, int n_in,
                              void* d_out, int out_size, void* d_ws, size_t ws_size,
                              hipStream_t stream) {
  const float* pts = (const float*)d_in[0];
  const float* f1  = (const float*)d_in[1];
  const float* f2  = (const float*)d_in[2];
  const float* wts = (const float*)d_in[3];
  float* out = (float*)d_out;
  char* ws = (char*)d_ws;

  unsigned short* f1b = (unsigned short*)(ws + OFF_F1B);
  unsigned short* f2b = (unsigned short*)(ws + OFF_F2B);
  float4* pp4 = (float4*)(ws + OFF_PP4);
  float* nb2 = (float*)(ws + OFF_NB2);
  float* pZf = (float*)(ws + OFF_PZF);
  float* Zp = (float*)(ws + OFF_ZP);
  float* Sp = (float*)(ws + OFF_SP);

  hipMemsetAsync(d_out, 0, 8 * sizeof(float), stream);
  hipMemsetAsync(ws + OFF_ZP, 0, CLR_BYTES, stream);

  prep_kernel<<<BN / 32, 256, 0, stream>>>(pts, f1, f2, f1b, f2b, pp4, nb2, out);

  dim3 grid(NN / 64, BB, CC);
  fea_kernel<<<grid, 256, 0, stream>>>(f1b, f2b, nb2, pZf);

  point_kernel<<<PT_BLOCKS, 256, 0, stream>>>(pp4, f1b, f2b, nb2, Zp, Sp);

  finalize_kernel<<<BN / 256, 256, 0, stream>>>(pZf, Zp, Sp, wts, out);
}

// Round 5
// 69.926 us; speedup vs baseline: 1.4631x; 1.1257x over previous
//
#include <hip/hip_runtime.h>
#include <hip/hip_bf16.h>

#define BB 4
#define NN 4096
#define DD 64
#define TJ 64
#define CC 8                 // fea column chunks (grid.z)
#define CHUNK (NN / CC)      // 512 cols per fea block
#define NTC (CHUNK / TJ)     // 8 tiles per fea block
#define PT_BLOCKS 512        // 8 rowgroups(2048 rows) * 64 jchunks(64 cols)
#define HPB 1024             // hit capacity per point block (expect ~88)
#define PREP_BLOCKS 512      // BN/32
#define FIN_BLOCKS 64        // BN/256
#define PSCALE 240.2244818f  // 200 * sqrt(log2(e)) : |p'i-p'j|^2 = PD*log2(e)
#define K2L 2.885390082f     // 2*log2(e)  (folded into f1 bf16)
#define NL2E -1.442695041f   // -log2(e)
#define LN2 0.6931471805599453f

typedef __attribute__((ext_vector_type(8))) short bf16x8;
typedef __attribute__((ext_vector_type(4))) float f32x4;

// workspace layout (bytes)
static constexpr size_t BN = (size_t)BB * NN;
static constexpr size_t OFF_F1B = 0;                          // bf16 [BN][D] (pre-scaled by K2L)
static constexpr size_t OFF_F2B = OFF_F1B + BN * DD * 2;      // bf16 [BN][D]
static constexpr size_t OFF_PP4 = OFF_F2B + BN * DD * 2;      // float4 [BN] {p'x,p'y,p'z,|p'|^2}
static constexpr size_t OFF_NB2 = OFF_PP4 + BN * 16;          // f32 [BN]  -|f2|^2*log2e
static constexpr size_t OFF_PZF = OFF_NB2 + BN * 4;           // f32 [CC][BN] partial Zf
static constexpr size_t OFF_ZP  = OFF_PZF + (size_t)CC * BN * 4;  // f32 [BN] (zeroed by prep)
static constexpr size_t OFF_SP  = OFF_ZP + BN * 4;            // f32 [BN] (zeroed by prep)
static constexpr size_t OFF_PRG = OFF_SP + BN * 4;            // f32 [PREP_BLOCKS] reg partials
static constexpr size_t OFF_CEP = OFF_PRG + PREP_BLOCKS * 4;  // f32 [FIN_BLOCKS] ce partials

__device__ __forceinline__ unsigned short f2bf(float x) {
  unsigned int u = __float_as_uint(x);
  u += 0x7FFFu + ((u >> 16) & 1u);   // round-to-nearest-even
  return (unsigned short)(u >> 16);
}
__device__ __forceinline__ float bf2f(short s) {
  return __uint_as_float(((unsigned)(unsigned short)s) << 16);
}
__device__ __forceinline__ void gl_lds16(const void* g, void* lds) {
  __builtin_amdgcn_global_load_lds((const __attribute__((address_space(1))) unsigned int*)g,
                                   (__attribute__((address_space(3))) unsigned int*)lds, 16, 0, 0);
}
__device__ __forceinline__ void gl_lds4(const void* g, void* lds) {
  __builtin_amdgcn_global_load_lds((const __attribute__((address_space(1))) unsigned int*)g,
                                   (__attribute__((address_space(3))) unsigned int*)lds, 4, 0, 0);
}

// ---- prep: bf16 convert (f1 scaled) + norms + points + reg partial + Zp/Sp zero ----
__global__ __launch_bounds__(256) void prep_kernel(
    const float* __restrict__ pts, const float* __restrict__ f1,
    const float* __restrict__ f2, unsigned short* __restrict__ f1b,
    unsigned short* __restrict__ f2b, float4* __restrict__ pp4,
    float* __restrict__ nb2, float* __restrict__ pregs,
    float* __restrict__ Zp, float* __restrict__ Sp) {
  const int R0 = blockIdx.x * 32;
  const int t = threadIdx.x;
  const float4* f1v = (const float4*)(f1 + (size_t)R0 * DD);
  const float4* f2v = (const float4*)(f2 + (size_t)R0 * DD);
  ushort4* o1 = (ushort4*)(f1b + (size_t)R0 * DD);
  ushort4* o2 = (ushort4*)(f2b + (size_t)R0 * DD);
  // zero Zp/Sp (32 rows per block)
  if (t < 32) { Zp[R0 + t] = 0.f; Sp[R0 + t] = 0.f; }
  float regsum = 0.f;
#pragma unroll
  for (int p = 0; p < 2; ++p) {
    int c = t + p * 256;                 // float4-chunk in [0,512); row = R0 + c/16
    float4 a = f1v[c], bv = f2v[c];
    ushort4 ua, ub;
    ua.x = f2bf(a.x * K2L); ua.y = f2bf(a.y * K2L);
    ua.z = f2bf(a.z * K2L); ua.w = f2bf(a.w * K2L);
    ub.x = f2bf(bv.x); ub.y = f2bf(bv.y); ub.z = f2bf(bv.z); ub.w = f2bf(bv.w);
    o1[c] = ua; o2[c] = ub;
    float s1 = a.x * a.x + a.y * a.y + a.z * a.z + a.w * a.w;
    float s2 = bv.x * bv.x + bv.y * bv.y + bv.z * bv.z + bv.w * bv.w;
    regsum += s1 + s2;
    float s2r = s2;
#pragma unroll
    for (int m = 1; m <= 8; m <<= 1) s2r += __shfl_xor(s2r, m, 64);
    if ((t & 15) == 0) nb2[R0 + (c >> 4)] = NL2E * s2r;
  }
  if (t < 32) {
    int row = R0 + t;
    float px = pts[row * 3 + 0] * PSCALE;
    float py = pts[row * 3 + 1] * PSCALE;
    float pz = pts[row * 3 + 2] * PSCALE;
    pp4[row] = make_float4(px, py, pz, fmaf(px, px, fmaf(py, py, pz * pz)));
  }
  __shared__ float red[256];
  red[t] = regsum;
  __syncthreads();
  for (int k = 128; k > 0; k >>= 1) {
    if (t < k) red[t] += red[t + k];
    __syncthreads();
  }
  if (t == 0) pregs[blockIdx.x] = red[0];
}

// ---------------- fea: Zf_i = sum_j 2^(K2L*dot + nb2_j) ----------------------
// grid (NN/64, BB, CC), block 256. Wave owns 16 rows x 512 cols (8 tiles).
__global__ __launch_bounds__(256) void fea_kernel(
    const unsigned short* __restrict__ f1b, const unsigned short* __restrict__ f2b,
    const float* __restrict__ nb2g, float* __restrict__ pZf) {
  __shared__ unsigned short f2t[2][TJ * DD];   // 16KB, XOR-swizzled 16B chunks in 128B rows
  __shared__ float b2t[2][TJ];                 // 512B

  const int b = blockIdx.y;
  const int ck = blockIdx.z;
  const int rowbase = blockIdx.x * 64;
  const int tid = threadIdx.x;
  const int wave = tid >> 6;
  const int lane = tid & 63;
  const int l15 = lane & 15;
  const int l4 = lane >> 4;

  const unsigned short* f1row = f1b + ((size_t)(b * NN + rowbase + wave * 16 + l15)) * DD;
  bf16x8 af0 = *(const bf16x8*)(f1row + l4 * 8);
  bf16x8 af1 = *(const bf16x8*)(f1row + 32 + l4 * 8);

  float Zf[4] = {0.f, 0.f, 0.f, 0.f};

  auto stage = [&](int buf, int col0) {
    const char* gbase = (const char*)(f2b + ((size_t)(b * NN + col0)) * DD);
    {
      int r = tid >> 3, s = tid & 7;
      gl_lds16(gbase + r * 128 + (s ^ (r & 7)) * 16, (char*)&f2t[buf][0] + wave * 1024);
    }
    {
      int c = tid + 256, r = c >> 3, s = c & 7;
      gl_lds16(gbase + r * 128 + (s ^ (r & 7)) * 16, (char*)&f2t[buf][0] + wave * 1024 + 4096);
    }
    if (wave == 1) gl_lds4(nb2g + (b * NN + col0 + lane), (char*)&b2t[buf][0]);
  };

  const int colbase = ck * CHUNK;
  stage(0, colbase);

  const int swz0 = ((l4 ^ (l15 & 7)) << 4);
  const int swz1 = (((4 + l4) ^ (l15 & 7)) << 4);

  for (int jt = 0; jt < NTC; ++jt) {
    __syncthreads();
    if (jt + 1 < NTC) stage((jt + 1) & 1, colbase + (jt + 1) * TJ);
    const int cur = jt & 1;
    const char* f2c = (const char*)f2t + cur * 8192 + l15 * 128;
#pragma unroll
    for (int s16 = 0; s16 < 4; ++s16) {
      bf16x8 bf0 = *(const bf16x8*)(f2c + swz0 + s16 * 2048);
      bf16x8 bf1 = *(const bf16x8*)(f2c + swz1 + s16 * 2048);
      float nb = b2t[cur][s16 * 16 + l15];
      f32x4 acc = {nb, nb, nb, nb};
      acc = __builtin_amdgcn_mfma_f32_16x16x32_bf16(af0, bf0, acc, 0, 0, 0);
      acc = __builtin_amdgcn_mfma_f32_16x16x32_bf16(af1, bf1, acc, 0, 0, 0);
#pragma unroll
      for (int r = 0; r < 4; ++r) Zf[r] += __builtin_amdgcn_exp2f(acc[r]);
    }
  }

#pragma unroll
  for (int m = 1; m <= 8; m <<= 1)
#pragma unroll
    for (int r = 0; r < 4; ++r) Zf[r] += __shfl_xor(Zf[r], m, 64);

  if (l15 == 0) {
    size_t base = (size_t)ck * BN + b * NN + rowbase + wave * 16 + l4 * 4;
#pragma unroll
    for (int r = 0; r < 4; ++r) pZf[base + r] = Zf[r];
  }
}

// ---------------- point: PD2 sparse hits -> Zp, Sp (fused resolve) ------------
__global__ __launch_bounds__(256) void point_kernel(
    const float4* __restrict__ pp4, const unsigned short* __restrict__ f1b,
    const unsigned short* __restrict__ f2b, const float* __restrict__ nb2g,
    float* __restrict__ Zp, float* __restrict__ Sp) {
  __shared__ __align__(16) float4 ptj[64];   // 1KB j-chunk points
  __shared__ uint2 hbuf[HPB];                // 8KB hit buffer
  __shared__ unsigned hcnt;
  const int pb = blockIdx.x;
  const int tid = threadIdx.x;
  const int rg = pb >> 6, jc = pb & 63;
  const int row0 = rg * 2048;                // global row base
  const int b = row0 >> 12;
  const int jcol0 = b * NN + jc * 64;

  if (tid == 0) hcnt = 0;
  if (tid < 64) gl_lds16(pp4 + jcol0 + tid, ptj);
  float m2x[8], m2y[8], m2z[8], xw[8];
#pragma unroll
  for (int k = 0; k < 8; ++k) {
    float4 p = pp4[row0 + k * 256 + tid];
    m2x[k] = -2.f * p.x; m2y[k] = -2.f * p.y; m2z[k] = -2.f * p.z; xw[k] = p.w;
  }
  __syncthreads();

#pragma unroll 4
  for (int jj = 0; jj < 64; ++jj) {
    float4 pj = ptj[jj];
    float pd[8];
#pragma unroll
    for (int k = 0; k < 8; ++k)
      pd[k] = fmaf(m2x[k], pj.x, fmaf(m2y[k], pj.y, fmaf(m2z[k], pj.z, xw[k] + pj.w)));
    float mn = fminf(fminf(fminf(pd[0], pd[1]), fminf(pd[2], pd[3])),
                     fminf(fminf(pd[4], pd[5]), fminf(pd[6], pd[7])));
    if (mn < 126.f) {
#pragma unroll
      for (int k = 0; k < 8; ++k)
        if (pd[k] < 126.f) {
          unsigned slot = atomicAdd(&hcnt, 1u);
          if (slot < HPB)
            hbuf[slot] = make_uint2(((unsigned)(k * 256 + tid) << 6) | (unsigned)jj,
                                    __float_as_uint(pd[k]));
        }
    }
  }
  __syncthreads();

  unsigned n = hcnt; if (n > HPB) n = HPB;
  for (unsigned idx = tid; idx < n; idx += 256) {
    uint2 h = hbuf[idx];
    unsigned rowg = row0 + (h.x >> 6);
    unsigned jg = jcol0 + (h.x & 63u);
    const bf16x8* A = (const bf16x8*)(f1b + (size_t)rowg * DD);
    const bf16x8* Bv = (const bf16x8*)(f2b + (size_t)jg * DD);
    float dot = 0.f;                         // = K2L * dot(f1,f2) (f1 pre-scaled)
#pragma unroll
    for (int c = 0; c < 8; ++c) {
      bf16x8 av = A[c], bv = Bv[c];
#pragma unroll
      for (int e = 0; e < 8; ++e) dot = fmaf(bf2f(av[e]), bf2f(bv[e]), dot);
    }
    float t2 = dot + nb2g[jg];               // (2dot - b2)*log2e
    float g = __builtin_amdgcn_exp2f(-__uint_as_float(h.y));
    atomicAdd(&Zp[rowg], g);
    atomicAdd(&Sp[rowg], g * t2);
  }
}

// ---------------- finalize: ce per row, partial per block ---------------------
__global__ __launch_bounds__(256) void finalize_kernel(
    const float* __restrict__ pZf, const float* __restrict__ Zp,
    const float* __restrict__ Sp, const float* __restrict__ wts,
    float* __restrict__ ceparts) {
  const int i = blockIdx.x * 256 + threadIdx.x;    // row in [0, BN)
  float zf = 0.f;
#pragma unroll
  for (int c = 0; c < CC; ++c) zf += pZf[(size_t)c * BN + i];
  float ce = wts[i] * (LN2 * (__builtin_amdgcn_logf(zf) - Sp[i] / Zp[i]));
  __shared__ float red[256];
  red[threadIdx.x] = ce;
  __syncthreads();
  for (int k = 128; k > 0; k >>= 1) {
    if (threadIdx.x < k) red[threadIdx.x] += red[threadIdx.x + k];
    __syncthreads();
  }
  if (threadIdx.x == 0) ceparts[blockIdx.x] = red[0];
}

// ---------------- out: reduce partials into d_out (plain stores) --------------
__global__ __launch_bounds__(256) void out_kernel(
    const float* __restrict__ ceparts, const float* __restrict__ pregs,
    float* __restrict__ out) {
  const int w = threadIdx.x >> 6, lane = threadIdx.x & 63;
  // reg: batch w spans pregs[w*128 .. w*128+127]
  float ps = pregs[w * 128 + lane] + pregs[w * 128 + 64 + lane];
#pragma unroll
  for (int m = 1; m <= 32; m <<= 1) ps += __shfl_xor(ps, m, 64);
  // ce: batch w spans ceparts[w*16 .. w*16+15]
  float cs = (lane < 16) ? ceparts[w * 16 + lane] : 0.f;
#pragma unroll
  for (int m = 1; m <= 8; m <<= 1) cs += __shfl_xor(cs, m, 64);
  if (lane == 0) {
    out[w] = cs;
    out[BB + w] = ps * (1.f / ((float)NN * DD));
  }
}

extern "C" void kernel_launch(void* const* d_in, const int* in_sizes, int n_in,
                              void* d_out, int out_size, void* d_ws, size_t ws_size,
                              hipStream_t stream) {
  const float* pts = (const float*)d_in[0];
  const float* f1  = (const float*)d_in[1];
  const float* f2  = (const float*)d_in[2];
  const float* wts = (const float*)d_in[3];
  float* out = (float*)d_out;
  char* ws = (char*)d_ws;

  unsigned short* f1b = (unsigned short*)(ws + OFF_F1B);
  unsigned short* f2b = (unsigned short*)(ws + OFF_F2B);
  float4* pp4 = (float4*)(ws + OFF_PP4);
  float* nb2 = (float*)(ws + OFF_NB2);
  float* pZf = (float*)(ws + OFF_PZF);
  float* Zp = (float*)(ws + OFF_ZP);
  float* Sp = (float*)(ws + OFF_SP);
  float* pregs = (float*)(ws + OFF_PRG);
  float* ceparts = (float*)(ws + OFF_CEP);

  prep_kernel<<<PREP_BLOCKS, 256, 0, stream>>>(pts, f1, f2, f1b, f2b, pp4, nb2,
                                               pregs, Zp, Sp);

  dim3 grid(NN / 64, BB, CC);
  fea_kernel<<<grid, 256, 0, stream>>>(f1b, f2b, nb2, pZf);

  point_kernel<<<PT_BLOCKS, 256, 0, stream>>>(pp4, f1b, f2b, nb2, Zp, Sp);

  finalize_kernel<<<FIN_BLOCKS, 256, 0, stream>>>(pZf, Zp, Sp, wts, ceparts);

  out_kernel<<<1, 256, 0, stream>>>(ceparts, pregs, out);
}

// Round 6
// 48.789 us; speedup vs baseline: 2.0970x; 1.4332x over previous
//
#include <hip/hip_runtime.h>
#include <hip/hip_bf16.h>

#define BB 4
#define NN 4096
#define DD 64
#define TJ 64
#define CC 8                 // column chunks (grid.z)
#define CHUNK (NN / CC)      // 512 cols per block
#define NTC (CHUNK / TJ)     // 8 tiles per block
#define HPB 1024             // hit capacity per dense block (expect ~30-160)
#define PREP_BLOCKS 512      // BN/32
#define FIN_BLOCKS 64        // BN/256
#define PSCALE 240.2244818f  // 200 * sqrt(log2(e)) : |p'i-p'j|^2 = PD*log2(e)
#define K2L 2.885390082f     // 2*log2(e)  (folded into f1 bf16)
#define NL2E -1.442695041f   // -log2(e)
#define LN2 0.6931471805599453f

typedef __attribute__((ext_vector_type(8))) short bf16x8;
typedef __attribute__((ext_vector_type(4))) float f32x4;

// workspace layout (bytes)
static constexpr size_t BN = (size_t)BB * NN;
static constexpr size_t OFF_F1B = 0;                          // bf16 [BN][D] (pre-scaled by K2L)
static constexpr size_t OFF_F2B = OFF_F1B + BN * DD * 2;      // bf16 [BN][D]
static constexpr size_t OFF_PP4 = OFF_F2B + BN * DD * 2;      // float4 [BN] {p'x,p'y,p'z,|p'|^2}
static constexpr size_t OFF_NB2 = OFF_PP4 + BN * 16;          // f32 [BN]  -|f2|^2*log2e
static constexpr size_t OFF_PZF = OFF_NB2 + BN * 4;           // f32 [CC][BN] partial Zf
static constexpr size_t OFF_ZP  = OFF_PZF + (size_t)CC * BN * 4;  // f32 [BN] (zeroed by prep)
static constexpr size_t OFF_SP  = OFF_ZP + BN * 4;            // f32 [BN] (zeroed by prep)
static constexpr size_t OFF_PRG = OFF_SP + BN * 4;            // f32 [PREP_BLOCKS] reg partials
static constexpr size_t OFF_CEP = OFF_PRG + PREP_BLOCKS * 4;  // f32 [FIN_BLOCKS] ce partials

__device__ __forceinline__ unsigned short f2bf(float x) {
  unsigned int u = __float_as_uint(x);
  u += 0x7FFFu + ((u >> 16) & 1u);   // round-to-nearest-even
  return (unsigned short)(u >> 16);
}
__device__ __forceinline__ float bf2f(short s) {
  return __uint_as_float(((unsigned)(unsigned short)s) << 16);
}
__device__ __forceinline__ void gl_lds16(const void* g, void* lds) {
  __builtin_amdgcn_global_load_lds((const __attribute__((address_space(1))) unsigned int*)g,
                                   (__attribute__((address_space(3))) unsigned int*)lds, 16, 0, 0);
}

// ---- prep: bf16 convert (f1 scaled) + norms + points + reg partial + Zp/Sp zero ----
__global__ __launch_bounds__(256) void prep_kernel(
    const float* __restrict__ pts, const float* __restrict__ f1,
    const float* __restrict__ f2, unsigned short* __restrict__ f1b,
    unsigned short* __restrict__ f2b, float4* __restrict__ pp4,
    float* __restrict__ nb2, float* __restrict__ pregs,
    float* __restrict__ Zp, float* __restrict__ Sp) {
  const int R0 = blockIdx.x * 32;
  const int t = threadIdx.x;
  const float4* f1v = (const float4*)(f1 + (size_t)R0 * DD);
  const float4* f2v = (const float4*)(f2 + (size_t)R0 * DD);
  ushort4* o1 = (ushort4*)(f1b + (size_t)R0 * DD);
  ushort4* o2 = (ushort4*)(f2b + (size_t)R0 * DD);
  if (t < 32) { Zp[R0 + t] = 0.f; Sp[R0 + t] = 0.f; }
  float regsum = 0.f;
#pragma unroll
  for (int p = 0; p < 2; ++p) {
    int c = t + p * 256;                 // float4-chunk in [0,512); row = R0 + c/16
    float4 a = f1v[c], bv = f2v[c];
    ushort4 ua, ub;
    ua.x = f2bf(a.x * K2L); ua.y = f2bf(a.y * K2L);
    ua.z = f2bf(a.z * K2L); ua.w = f2bf(a.w * K2L);
    ub.x = f2bf(bv.x); ub.y = f2bf(bv.y); ub.z = f2bf(bv.z); ub.w = f2bf(bv.w);
    o1[c] = ua; o2[c] = ub;
    float s1 = a.x * a.x + a.y * a.y + a.z * a.z + a.w * a.w;
    float s2 = bv.x * bv.x + bv.y * bv.y + bv.z * bv.z + bv.w * bv.w;
    regsum += s1 + s2;
    float s2r = s2;
#pragma unroll
    for (int m = 1; m <= 8; m <<= 1) s2r += __shfl_xor(s2r, m, 64);
    if ((t & 15) == 0) nb2[R0 + (c >> 4)] = NL2E * s2r;
  }
  if (t < 32) {
    int row = R0 + t;
    float px = pts[row * 3 + 0] * PSCALE;
    float py = pts[row * 3 + 1] * PSCALE;
    float pz = pts[row * 3 + 2] * PSCALE;
    pp4[row] = make_float4(px, py, pz, fmaf(px, px, fmaf(py, py, pz * pz)));
  }
  __shared__ float red[256];
  red[t] = regsum;
  __syncthreads();
  for (int k = 128; k > 0; k >>= 1) {
    if (t < k) red[t] += red[t + k];
    __syncthreads();
  }
  if (t == 0) pregs[blockIdx.x] = red[0];
}

// ---------------- dense: Zf (MFMA+exp2) + point hit-scan + in-block resolve ----
// grid (NN/128, BB, CC), block 256. Wave owns 32 rows x 512 cols; block 128 rows.
__global__ __launch_bounds__(256, 4) void dense_kernel(
    const unsigned short* __restrict__ f1b, const unsigned short* __restrict__ f2b,
    const float4* __restrict__ pp4, const float* __restrict__ nb2g,
    float* __restrict__ pZf, float* __restrict__ Zp, float* __restrict__ Sp) {
  __shared__ unsigned short f2t[2][TJ * DD];   // 16KB, XOR-swizzled 16B chunks in 128B rows
  __shared__ uint2 hbuf[HPB];                  // 8KB hit buffer
  __shared__ unsigned hcnt;

  const int b = blockIdx.y;
  const int ck = blockIdx.z;
  const int rowbase = blockIdx.x * 128;
  const int tid = threadIdx.x;
  const int wave = tid >> 6;
  const int lane = tid & 63;
  const int l15 = lane & 15;
  const int l4 = lane >> 4;
  if (tid == 0) hcnt = 0;

  // A fragments: 2 row-subtiles of 16 (wave rows = rowbase + wave*32 .. +32)
  const int wrow = rowbase + wave * 32;
  bf16x8 af[2][2];
#pragma unroll
  for (int rt = 0; rt < 2; ++rt) {
    const unsigned short* fr = f1b + ((size_t)(b * NN + wrow + rt * 16 + l15)) * DD;
    af[rt][0] = *(const bf16x8*)(fr + l4 * 8);
    af[rt][1] = *(const bf16x8*)(fr + 32 + l4 * 8);
  }
  // point-scan row constants: 4 rows per thread (rows fixed for whole block)
  float m2x[4], m2y[4], m2z[4], xw[4];
#pragma unroll
  for (int k = 0; k < 4; ++k) {
    float4 p = pp4[b * NN + rowbase + (tid & 31) * 4 + k];
    m2x[k] = -2.f * p.x; m2y[k] = -2.f * p.y; m2z[k] = -2.f * p.z; xw[k] = p.w;
  }

  float Zf[2][4];
#pragma unroll
  for (int rt = 0; rt < 2; ++rt)
#pragma unroll
    for (int r = 0; r < 4; ++r) Zf[rt][r] = 0.f;

  auto stage = [&](int buf, int col0) {
    const char* gbase = (const char*)(f2b + ((size_t)(b * NN + col0)) * DD);
    {
      int r = tid >> 3, s = tid & 7;
      gl_lds16(gbase + r * 128 + (s ^ (r & 7)) * 16, (char*)&f2t[buf][0] + wave * 1024);
    }
    {
      int c = tid + 256, r = c >> 3, s = c & 7;
      gl_lds16(gbase + r * 128 + (s ^ (r & 7)) * 16, (char*)&f2t[buf][0] + wave * 1024 + 4096);
    }
  };

  const int colbase = ck * CHUNK;
  stage(0, colbase);

  const int swz0 = ((l4 ^ (l15 & 7)) << 4);
  const int swz1 = (((4 + l4) ^ (l15 & 7)) << 4);
  const float4* pcol = pp4 + b * NN + colbase;      // batch-local col points
  const float* nbcol = nb2g + b * NN + colbase;

  for (int jt = 0; jt < NTC; ++jt) {
    __syncthreads();
    if (jt + 1 < NTC) stage((jt + 1) & 1, colbase + (jt + 1) * TJ);
    const int cur = jt & 1;
    const char* f2c = (const char*)f2t + cur * 8192 + l15 * 128;
    // --- fea: 4 sub-tiles of 16 cols ---
#pragma unroll
    for (int s16 = 0; s16 < 4; ++s16) {
      bf16x8 bf0 = *(const bf16x8*)(f2c + swz0 + s16 * 2048);
      bf16x8 bf1 = *(const bf16x8*)(f2c + swz1 + s16 * 2048);
      float nb = nbcol[jt * 64 + s16 * 16 + l15];   // L1-hit global, off the LDS pipe
      f32x4 a0 = {nb, nb, nb, nb}, a1 = a0;
      a0 = __builtin_amdgcn_mfma_f32_16x16x32_bf16(af[0][0], bf0, a0, 0, 0, 0);
      a0 = __builtin_amdgcn_mfma_f32_16x16x32_bf16(af[0][1], bf1, a0, 0, 0, 0);
      a1 = __builtin_amdgcn_mfma_f32_16x16x32_bf16(af[1][0], bf0, a1, 0, 0, 0);
      a1 = __builtin_amdgcn_mfma_f32_16x16x32_bf16(af[1][1], bf1, a1, 0, 0, 0);
#pragma unroll
      for (int r = 0; r < 4; ++r) {
        Zf[0][r] += __builtin_amdgcn_exp2f(a0[r]);
        Zf[1][r] += __builtin_amdgcn_exp2f(a1[r]);
      }
    }
    // --- point scan: this thread: 4 rows x 8 cols of the 128x64 tile ---
#pragma unroll
    for (int g = 0; g < 2; ++g) {
      int c0 = jt * 64 + (tid >> 5) * 8 + g * 4;    // CHUNK-local col
      float4 pj0 = pcol[c0], pj1 = pcol[c0 + 1], pj2 = pcol[c0 + 2], pj3 = pcol[c0 + 3];
      float pd[4][4];
#pragma unroll
      for (int k = 0; k < 4; ++k) {
        pd[0][k] = fmaf(m2x[k], pj0.x, fmaf(m2y[k], pj0.y, fmaf(m2z[k], pj0.z, xw[k] + pj0.w)));
        pd[1][k] = fmaf(m2x[k], pj1.x, fmaf(m2y[k], pj1.y, fmaf(m2z[k], pj1.z, xw[k] + pj1.w)));
        pd[2][k] = fmaf(m2x[k], pj2.x, fmaf(m2y[k], pj2.y, fmaf(m2z[k], pj2.z, xw[k] + pj2.w)));
        pd[3][k] = fmaf(m2x[k], pj3.x, fmaf(m2y[k], pj3.y, fmaf(m2z[k], pj3.z, xw[k] + pj3.w)));
      }
      float mn = 999.f;
#pragma unroll
      for (int c = 0; c < 4; ++c)
#pragma unroll
        for (int k = 0; k < 4; ++k) mn = fminf(mn, pd[c][k]);
      if (mn < 126.f) {
#pragma unroll
        for (int c = 0; c < 4; ++c)
#pragma unroll
          for (int k = 0; k < 4; ++k)
            if (pd[c][k] < 126.f) {
              unsigned slot = atomicAdd(&hcnt, 1u);
              if (slot < HPB)
                hbuf[slot] = make_uint2(
                    (((unsigned)((tid & 31) * 4 + k)) << 9) | (unsigned)(c0 + c),
                    __float_as_uint(pd[c][k]));
            }
      }
    }
  }

  // merge Zf across the 16 lanes sharing rows; write partials
#pragma unroll
  for (int m = 1; m <= 8; m <<= 1)
#pragma unroll
    for (int rt = 0; rt < 2; ++rt)
#pragma unroll
      for (int r = 0; r < 4; ++r) Zf[rt][r] += __shfl_xor(Zf[rt][r], m, 64);
  if (l15 == 0) {
    size_t base = (size_t)ck * BN + b * NN + wrow + l4 * 4;
#pragma unroll
    for (int rt = 0; rt < 2; ++rt)
#pragma unroll
      for (int r = 0; r < 4; ++r) pZf[base + rt * 16 + r] = Zf[rt][r];
  }

  // resolve hits: recompute bf16 dot, accumulate global Zp/Sp
  __syncthreads();
  unsigned n = hcnt; if (n > HPB) n = HPB;
  for (unsigned idx = tid; idx < n; idx += 256) {
    uint2 h = hbuf[idx];
    unsigned rowg = b * NN + rowbase + (h.x >> 9);
    unsigned jg = b * NN + colbase + (h.x & 511u);
    const bf16x8* A = (const bf16x8*)(f1b + (size_t)rowg * DD);
    const bf16x8* Bv = (const bf16x8*)(f2b + (size_t)jg * DD);
    float dot = 0.f;                       // = K2L * dot(f1,f2)  (f1 pre-scaled)
#pragma unroll
    for (int c = 0; c < 8; ++c) {
      bf16x8 av = A[c], bv = Bv[c];
#pragma unroll
      for (int e = 0; e < 8; ++e) dot = fmaf(bf2f(av[e]), bf2f(bv[e]), dot);
    }
    float t2 = dot + nb2g[jg];             // (2dot - b2)*log2e
    float g = __builtin_amdgcn_exp2f(-__uint_as_float(h.y));
    atomicAdd(&Zp[rowg], g);
    atomicAdd(&Sp[rowg], g * t2);
  }
}

// ---------------- finalize: ce per row, partial per block ---------------------
__global__ __launch_bounds__(256) void finalize_kernel(
    const float* __restrict__ pZf, const float* __restrict__ Zp,
    const float* __restrict__ Sp, const float* __restrict__ wts,
    float* __restrict__ ceparts) {
  const int i = blockIdx.x * 256 + threadIdx.x;    // row in [0, BN)
  float zf = 0.f;
#pragma unroll
  for (int c = 0; c < CC; ++c) zf += pZf[(size_t)c * BN + i];
  float ce = wts[i] * (LN2 * (__builtin_amdgcn_logf(zf) - Sp[i] / Zp[i]));
  __shared__ float red[256];
  red[threadIdx.x] = ce;
  __syncthreads();
  for (int k = 128; k > 0; k >>= 1) {
    if (threadIdx.x < k) red[threadIdx.x] += red[threadIdx.x + k];
    __syncthreads();
  }
  if (threadIdx.x == 0) ceparts[blockIdx.x] = red[0];
}

// ---------------- out: reduce partials into d_out (plain stores) --------------
__global__ __launch_bounds__(256) void out_kernel(
    const float* __restrict__ ceparts, const float* __restrict__ pregs,
    float* __restrict__ out) {
  const int w = threadIdx.x >> 6, lane = threadIdx.x & 63;
  float ps = pregs[w * 128 + lane] + pregs[w * 128 + 64 + lane];
#pragma unroll
  for (int m = 1; m <= 32; m <<= 1) ps += __shfl_xor(ps, m, 64);
  float cs = (lane < 16) ? ceparts[w * 16 + lane] : 0.f;
#pragma unroll
  for (int m = 1; m <= 8; m <<= 1) cs += __shfl_xor(cs, m, 64);
  if (lane == 0) {
    out[w] = cs;
    out[BB + w] = ps * (1.f / ((float)NN * DD));
  }
}

extern "C" void kernel_launch(void* const* d_in, const int* in_sizes, int n_in,
                              void* d_out, int out_size, void* d_ws, size_t ws_size,
                              hipStream_t stream) {
  const float* pts = (const float*)d_in[0];
  const float* f1  = (const float*)d_in[1];
  const float* f2  = (const float*)d_in[2];
  const float* wts = (const float*)d_in[3];
  float* out = (float*)d_out;
  char* ws = (char*)d_ws;

  unsigned short* f1b = (unsigned short*)(ws + OFF_F1B);
  unsigned short* f2b = (unsigned short*)(ws + OFF_F2B);
  float4* pp4 = (float4*)(ws + OFF_PP4);
  float* nb2 = (float*)(ws + OFF_NB2);
  float* pZf = (float*)(ws + OFF_PZF);
  float* Zp = (float*)(ws + OFF_ZP);
  float* Sp = (float*)(ws + OFF_SP);
  float* pregs = (float*)(ws + OFF_PRG);
  float* ceparts = (float*)(ws + OFF_CEP);

  prep_kernel<<<PREP_BLOCKS, 256, 0, stream>>>(pts, f1, f2, f1b, f2b, pp4, nb2,
                                               pregs, Zp, Sp);

  dim3 grid(NN / 128, BB, CC);
  dense_kernel<<<grid, 256, 0, stream>>>(f1b, f2b, pp4, nb2, pZf, Zp, Sp);

  finalize_kernel<<<FIN_BLOCKS, 256, 0, stream>>>(pZf, Zp, Sp, wts, ceparts);

  out_kernel<<<1, 256, 0, stream>>>(ceparts, pregs, out);
}